// Round 1
// baseline (135.510 us; speedup 1.0000x reference)
//
#include <hip/hip_runtime.h>

// YOLO decode: 3 scales, B=128, 45 channels = 3 anchors x (iou, dx, dy, dw, dh, 10 classes)
// Output: boxes [NTOT,6] fp32 then mask [NTOT] as 0/1 fp32.

constexpr int  BATCH = 128;
constexpr long N13 = 128L * 13 * 13 * 3;   //   64896
constexpr long N26 = 128L * 26 * 26 * 3;   //  259584
constexpr long N52 = 128L * 52 * 52 * 3;   // 1038336
constexpr long NTOT = N13 + N26 + N52;     // 1362816

template <int H, int STRIDE, long ROWOFF>
__global__ __launch_bounds__(256) void decode_scale(
    const float* __restrict__ o,      // [B,45,H,H]
    const float* __restrict__ anc,    // [3,2]
    const float* __restrict__ threshp,
    float* __restrict__ out)
{
    const long N = (long)BATCH * H * H * 3;
    long rel = (long)blockIdx.x * blockDim.x + threadIdx.x;
    if (rel >= N) return;

    const float thresh = *threshp;

    // rel = ((b*H + y)*H + x)*3 + a   (anchor-fastest -> output row == ROWOFF+rel)
    int a = (int)(rel % 3);
    long cell = rel / 3;
    int x = (int)(cell % H);
    long t = cell / H;
    int y = (int)(t % H);
    int b = (int)(t / H);

    const long hw = (long)H * H;
    const float* p = o + (long)(b * 45 + a * 15) * hw + (long)y * H + x;

    float v[15];
#pragma unroll
    for (int j = 0; j < 15; ++j) v[j] = p[j * hw];

    float iou = v[0];
    float px = ((float)x + v[1]) * (float)STRIDE;
    float py = ((float)y + v[2]) * (float)STRIDE;
    float pw = anc[2 * a + 0] * expf(v[3]);
    float ph = anc[2 * a + 1] * expf(v[4]);

    // argmax over classes, first-max tie-break (matches jnp.argmax)
    int kind = 0;
    float best = v[5];
#pragma unroll
    for (int c = 1; c < 10; ++c) {
        if (v[5 + c] > best) { best = v[5 + c]; kind = c; }
    }

    long row = ROWOFF + rel;
    float2* orow = (float2*)out + row * 3;
    orow[0] = make_float2(iou, px - 0.5f * pw);
    orow[1] = make_float2(py - 0.5f * ph, px + 0.5f * pw);
    orow[2] = make_float2(py + 0.5f * ph, (float)kind);

    out[6 * NTOT + row] = (iou > thresh) ? 1.0f : 0.0f;
}

extern "C" void kernel_launch(void* const* d_in, const int* in_sizes, int n_in,
                              void* d_out, int out_size, void* d_ws, size_t ws_size,
                              hipStream_t stream) {
    const float* o13 = (const float*)d_in[0];
    const float* o26 = (const float*)d_in[1];
    const float* o52 = (const float*)d_in[2];
    const float* a13 = (const float*)d_in[3];
    const float* a26 = (const float*)d_in[4];
    const float* a52 = (const float*)d_in[5];
    const float* thr = (const float*)d_in[6];
    float* out = (float*)d_out;

    const int block = 256;
    decode_scale<13, 32, 0L>
        <<<(N13 + block - 1) / block, block, 0, stream>>>(o13, a13, thr, out);
    decode_scale<26, 16, N13>
        <<<(N26 + block - 1) / block, block, 0, stream>>>(o26, a26, thr, out);
    decode_scale<52, 8, N13 + N26>
        <<<(N52 + block - 1) / block, block, 0, stream>>>(o52, a52, thr, out);
}